// Round 2
// baseline (6843.715 us; speedup 1.0000x reference)
//
#include <hip/hip_runtime.h>
#include <hip/hip_bf16.h>

// Problem dims
#define B_ 128
#define T_ 256
#define F_ 512
#define U_ 1024

typedef __attribute__((ext_vector_type(8))) short short8;   // 8 bf16 MFMA A/B frag (4 VGPRs)
typedef __attribute__((ext_vector_type(4))) float f32x4;    // MFMA C/D frag

// Workspace layout (needs 2048 + 2*524288 bytes ≈ 1.05 MB):
//   [0, 2048)            : barrier counters (512 ints; cnt[g] at 256 + g*32)
//   [2048, +512KB)       : s_hi[2 parity][128 b][1024 u]  bf16 (as short)
//   [2048+512KB, +512KB) : s_lo[2 parity][128 b][1024 u]  bf16

// ---------------------------------------------------------------------------
// Kernel 0: init — zero barrier area, prefill parity-1 state buffers with
// split(x0) broadcast across the 128 batch rows. Grid 512 x 256.
// ---------------------------------------------------------------------------
__global__ __launch_bounds__(256) void init_kernel(
    const float* __restrict__ x0, short* __restrict__ shi,
    short* __restrict__ slo, int* __restrict__ wsbar) {
  const int tid = threadIdx.x;
  if (blockIdx.x == 0) { wsbar[tid] = 0; wsbar[tid + 256] = 0; }
  const int idx = blockIdx.x * 256 + tid;   // 0..131071
  const int k = idx & 1023;
  const int b = idx >> 10;                  // 0..127
  const float x = x0[k];
  const unsigned ux = __float_as_uint(x);
  const unsigned h  = ux & 0xFFFF0000u;
  const float l     = x - __uint_as_float(h);
  const size_t sidx = (size_t)(128 + b) * U_ + k;   // parity 1
  shi[sidx] = (short)(h >> 16);
  slo[sidx] = (short)(__float_as_uint(l) >> 16);
}

// ---------------------------------------------------------------------------
// Kernel A: h[b,t,u] = inputs[b,t,:] @ R[:,u] + bias[u], written into
// out[(b*257+t)*1024 + u] (recurrence overwrites these slots with s_t).
// WG = 256 thr (4 waves), tile M=64 x N=64, K-chunks of 32, split-bf16 MFMA.
// ---------------------------------------------------------------------------
__global__ __launch_bounds__(256) void hproj_kernel(
    const float* __restrict__ inp, const float* __restrict__ R,
    const float* __restrict__ bias, float* __restrict__ out) {
  __shared__ short bt_hi[64][40];   // B chunk transposed [n][k]; 80B rows (16B-aligned)
  __shared__ short bt_lo[64][40];

  const int tid  = threadIdx.x;
  const int mblk = blockIdx.x >> 4;    // 0..511
  const int nblk = blockIdx.x & 15;    // 0..15
  const int n0   = nblk * 64;
  const int wave = tid >> 6, lane = tid & 63;
  const int lm   = lane & 15, quad = lane >> 4;
  const int r0   = mblk * 64 + wave * 16;

  f32x4 c[4] = {{0,0,0,0},{0,0,0,0},{0,0,0,0},{0,0,0,0}};

  for (int kc = 0; kc < 16; ++kc) {
    const int k0 = kc * 32;
    // stage B chunk (32k x 64n), transposed + hi/lo split
    {
      const int kr = tid >> 3;        // 0..31
      const int ns = (tid & 7) * 8;   // 0..56
      const float* p = R + (size_t)(k0 + kr) * U_ + n0 + ns;
      float4 va = *(const float4*)p;
      float4 vb = *(const float4*)(p + 4);
      float v[8] = {va.x, va.y, va.z, va.w, vb.x, vb.y, vb.z, vb.w};
#pragma unroll
      for (int i = 0; i < 8; ++i) {
        const unsigned ux = __float_as_uint(v[i]);
        const unsigned h  = ux & 0xFFFF0000u;
        const float l     = v[i] - __uint_as_float(h);
        bt_hi[ns + i][kr] = (short)(h >> 16);
        bt_lo[ns + i][kr] = (short)(__float_as_uint(l) >> 16);
      }
    }
    __syncthreads();

    // A frag direct from global: A[m = lane&15][k = quad*8+j]
    const float* ap = inp + (size_t)(r0 + lm) * F_ + k0 + quad * 8;
    float4 aa = *(const float4*)ap;
    float4 ab = *(const float4*)(ap + 4);
    float av[8] = {aa.x, aa.y, aa.z, aa.w, ab.x, ab.y, ab.z, ab.w};
    short8 ahi, alo;
#pragma unroll
    for (int i = 0; i < 8; ++i) {
      const unsigned ux = __float_as_uint(av[i]);
      const unsigned h  = ux & 0xFFFF0000u;
      const float l     = av[i] - __uint_as_float(h);
      ahi[i] = (short)(h >> 16);
      alo[i] = (short)(__float_as_uint(l) >> 16);
    }

#pragma unroll
    for (int nt = 0; nt < 4; ++nt) {
      short8 bhi = *(const short8*)&bt_hi[nt * 16 + lm][quad * 8];
      short8 blo = *(const short8*)&bt_lo[nt * 16 + lm][quad * 8];
      c[nt] = __builtin_amdgcn_mfma_f32_16x16x32_bf16(ahi, bhi, c[nt], 0, 0, 0);
      c[nt] = __builtin_amdgcn_mfma_f32_16x16x32_bf16(ahi, blo, c[nt], 0, 0, 0);
      c[nt] = __builtin_amdgcn_mfma_f32_16x16x32_bf16(alo, bhi, c[nt], 0, 0, 0);
    }
    __syncthreads();
  }

  // epilogue: + bias; C layout: col=lane&15, row=quad*4+reg
#pragma unroll
  for (int nt = 0; nt < 4; ++nt) {
    const int u = n0 + nt * 16 + lm;
    const float bv = bias[u];
#pragma unroll
    for (int r = 0; r < 4; ++r) {
      const int row = r0 + quad * 4 + r;    // row = b*256 + t
      const int b   = row >> 8;
      out[(size_t)(row + b) * U_ + u] = c[nt][r] + bv;   // slot (b*257+t)
    }
  }
}

// ---------------------------------------------------------------------------
// Kernel B: persistent recurrence. Grid = 256 WGs x 256 thr; LDS = 2 KB
// (static) so capacity is >=2 WGs/CU -> all 256 WGs trivially co-resident.
// WG (bb,cb): batch rows bb*16..+16, units cb*32..+32. Waves: nt = wv&1
// (16-unit col tile), kh = wv>>1 (512-wide K half). W fragments (hi/lo bf16)
// preloaded into 128 VGPRs per wave — hot loop is pure load + 3xMFMA.
// State exchange via pre-split bf16 hi/lo double buffers in d_ws; sync via 8
// independent per-batch-group monotone counters (32 WGs each).
// ---------------------------------------------------------------------------
__global__ __launch_bounds__(256) void recur_kernel(
    const float* __restrict__ W, float* __restrict__ out,
    int* __restrict__ wsbar, short* __restrict__ shi, short* __restrict__ slo) {
  __shared__ float red[2 * 64 * 4];   // [nt][lane][4]

  const int tid  = threadIdx.x;
  const int wv   = tid >> 6, lane = tid & 63;
  const int lm   = lane & 15, quad = lane >> 4;
  const int nt   = wv & 1, kh = wv >> 1;
  const int bb   = blockIdx.x >> 5;   // 0..7
  const int cb   = blockIdx.x & 31;   // 0..31
  const int u0   = cb * 32;
  const int u    = u0 + nt * 16 + lm;

  // ---- preload W fragments into registers (one-time) ----
  // B-frag: lane holds W[k = kk*32 + quad*8 + j][u], j=0..7, for kk=kh*16+ks
  short8 wh[16], wl[16];
  {
    const float* wp = W + (size_t)(kh * 512 + quad * 8) * U_ + u;
#pragma unroll
    for (int ks = 0; ks < 16; ++ks) {
#pragma unroll
      for (int j = 0; j < 8; ++j) {
        const float x = wp[(size_t)(ks * 32 + j) * U_];
        const unsigned ux = __float_as_uint(x);
        const unsigned h  = ux & 0xFFFF0000u;
        const float l     = x - __uint_as_float(h);
        wh[ks][j] = (short)(h >> 16);
        wl[ks][j] = (short)(__float_as_uint(l) >> 16);
      }
    }
  }

  float accE[4] = {0.f, 0.f, 0.f, 0.f};
  int* const cntp = wsbar + 256 + bb * 32;

  // A-frag base: row = bb*16 + lm, k = kh*512 + ks*32 + quad*8
  const short* const ah_base = shi + (size_t)(bb * 16 + lm) * U_ + kh * 512 + quad * 8;
  const short* const al_base = slo + (size_t)(bb * 16 + lm) * U_ + kh * 512 + quad * 8;

  for (int t = 0; t < T_; ++t) {
    const int pr = (t + 1) & 1;           // parity holding s_{t-1}
    const short* ah = ah_base + (size_t)pr * 128 * U_;
    const short* al = al_base + (size_t)pr * 128 * U_;

    f32x4 c = {0, 0, 0, 0};
#pragma unroll
    for (int ks = 0; ks < 16; ++ks) {
      short8 a_hi = *(const short8*)(ah + ks * 32);
      short8 a_lo = *(const short8*)(al + ks * 32);
      c = __builtin_amdgcn_mfma_f32_16x16x32_bf16(a_hi, wh[ks], c, 0, 0, 0);
      c = __builtin_amdgcn_mfma_f32_16x16x32_bf16(a_hi, wl[ks], c, 0, 0, 0);
      c = __builtin_amdgcn_mfma_f32_16x16x32_bf16(a_lo, wh[ks], c, 0, 0, 0);
    }

    // cross-wave K reduction (kh=1 partials -> kh=0)
    if (kh == 1) *(f32x4*)&red[(nt * 64 + lane) * 4] = c;
    __syncthreads();
    if (kh == 0) {
      f32x4 p = *(const f32x4*)&red[(nt * 64 + lane) * 4];
      c += p;
      const int pw = t & 1;               // parity receiving s_t
#pragma unroll
      for (int r = 0; r < 4; ++r) {
        const int row = bb * 16 + quad * 4 + r;
        const size_t idx = (size_t)(row * 257 + t) * U_ + u;
        const float s = tanhf(c[r] + out[idx]);
        out[idx] = s;
        accE[r] += __expf(s);
        const unsigned ux = __float_as_uint(s);
        const unsigned h  = ux & 0xFFFF0000u;
        const float l     = s - __uint_as_float(h);
        const size_t sidx = (size_t)(pw * 128 + row) * U_ + u;
        shi[sidx] = (short)(h >> 16);
        slo[sidx] = (short)(__float_as_uint(l) >> 16);
      }
    }
    __syncthreads();   // drain epilogue stores of waves 0/1 (waitcnt before s_barrier)

    // ---- per-batch-group barrier (32 WGs), monotone counter ----
    if (tid == 0) {
      __threadfence();  // agent-scope: write back local L2 (covers all waves' stores)
      __hip_atomic_fetch_add(cntp, 1, __ATOMIC_ACQ_REL, __HIP_MEMORY_SCOPE_AGENT);
      const int target = 32 * (t + 1);
      while (__hip_atomic_load(cntp, __ATOMIC_ACQUIRE, __HIP_MEMORY_SCOPE_AGENT) < target) {
        __builtin_amdgcn_s_sleep(1);
      }
    }
    __syncthreads();
  }

  // terminal: out[b, 256, u] = log(tanh(mean_t exp(s_t)))   (beta = 1)
  if (kh == 0) {
#pragma unroll
    for (int r = 0; r < 4; ++r) {
      const int row = bb * 16 + quad * 4 + r;
      const size_t idx = (size_t)(row * 257 + T_) * U_ + u;
      out[idx] = logf(tanhf(accE[r] * (1.0f / 256.0f)));
    }
  }
}

extern "C" void kernel_launch(void* const* d_in, const int* in_sizes, int n_in,
                              void* d_out, int out_size, void* d_ws, size_t ws_size,
                              hipStream_t stream) {
  (void)in_sizes; (void)n_in; (void)out_size; (void)ws_size;
  const float* inp  = (const float*)d_in[0];
  const float* R    = (const float*)d_in[1];
  const float* W    = (const float*)d_in[2];
  const float* bias = (const float*)d_in[3];
  const float* x0   = (const float*)d_in[4];
  float* out = (float*)d_out;
  int*   wsbar = (int*)d_ws;
  short* shi = (short*)((char*)d_ws + 2048);
  short* slo = shi + 2 * 128 * 1024;

  init_kernel<<<dim3(512), dim3(256), 0, stream>>>(x0, shi, slo, wsbar);
  hproj_kernel<<<dim3(8192), dim3(256), 0, stream>>>(inp, R, bias, out);
  recur_kernel<<<dim3(256), dim3(256), 0, stream>>>(W, out, wsbar, shi, slo);
}

// Round 3
// 2767.815 us; speedup vs baseline: 2.4726x; 2.4726x over previous
//
#include <hip/hip_runtime.h>
#include <hip/hip_bf16.h>

// Problem dims
#define B_ 128
#define T_ 256
#define F_ 512
#define U_ 1024

typedef __attribute__((ext_vector_type(8))) short short8;   // 8 bf16 MFMA A/B frag (4 VGPRs)
typedef __attribute__((ext_vector_type(4))) float f32x4;    // MFMA C/D frag

// Workspace layout:
//   [0, 2048)        : barrier counters (cnt[g] at int offset 256 + g*32)
//   [2048, +512KB)   : s_hi[8 group][2 parity][16384]  bf16 frag-layout
//   [.. , +512KB)    : s_lo[8 group][2 parity][16384]
// Frag layout within a 16384-short region: elem (row 0..15, k 0..1023) at
//   ((k>>3)*16 + row)*8 + (k&7)   -- identical to LDS layout, so the
// consumer's global->LDS copy is a straight linear memcpy and ds_read_b128
// yields MFMA A-frags with perfect coalescing (1 KB contiguous per wave).

#define SB_REGION 16384   // shorts per (group,parity) region

// ---------------------------------------------------------------------------
// Kernel 0: zero barrier counters; prefill parity-1 state with split(x0)
// broadcast across rows, in frag layout. Plain stores (kernel-end flush
// makes them visible device-wide before recur starts).
// ---------------------------------------------------------------------------
__global__ __launch_bounds__(256) void init_kernel(
    const float* __restrict__ x0, short* __restrict__ shi,
    short* __restrict__ slo, int* __restrict__ wsbar) {
  const int tid = threadIdx.x;
  if (blockIdx.x == 0) { wsbar[tid] = 0; wsbar[tid + 256] = 0; }
  const int idx = blockIdx.x * 256 + tid;   // 0..131071 = 8g * 16row * 1024k
  const int k   = idx & 1023;
  const int row = (idx >> 10) & 15;
  const int g   = idx >> 14;
  const float x = x0[k];
  const unsigned ux = __float_as_uint(x);
  const unsigned h  = ux & 0xFFFF0000u;
  const float l     = x - __uint_as_float(h);
  const size_t sidx = (size_t)(g * 2 + 1) * SB_REGION + ((size_t)(k >> 3) * 16 + row) * 8 + (k & 7);
  shi[sidx] = (short)(h >> 16);
  slo[sidx] = (short)(__float_as_uint(l) >> 16);
}

// ---------------------------------------------------------------------------
// Kernel A: h[b,t,u] = inputs[b,t,:] @ R[:,u] + bias[u] -> out[(b*257+t)*1024+u]
// (unchanged from round 2 — passed correctness).
// ---------------------------------------------------------------------------
__global__ __launch_bounds__(256) void hproj_kernel(
    const float* __restrict__ inp, const float* __restrict__ R,
    const float* __restrict__ bias, float* __restrict__ out) {
  __shared__ short bt_hi[64][40];
  __shared__ short bt_lo[64][40];

  const int tid  = threadIdx.x;
  const int mblk = blockIdx.x >> 4;
  const int nblk = blockIdx.x & 15;
  const int n0   = nblk * 64;
  const int wave = tid >> 6, lane = tid & 63;
  const int lm   = lane & 15, quad = lane >> 4;
  const int r0   = mblk * 64 + wave * 16;

  f32x4 c[4] = {{0,0,0,0},{0,0,0,0},{0,0,0,0},{0,0,0,0}};

  for (int kc = 0; kc < 16; ++kc) {
    const int k0 = kc * 32;
    {
      const int kr = tid >> 3;
      const int ns = (tid & 7) * 8;
      const float* p = R + (size_t)(k0 + kr) * U_ + n0 + ns;
      float4 va = *(const float4*)p;
      float4 vb = *(const float4*)(p + 4);
      float v[8] = {va.x, va.y, va.z, va.w, vb.x, vb.y, vb.z, vb.w};
#pragma unroll
      for (int i = 0; i < 8; ++i) {
        const unsigned ux = __float_as_uint(v[i]);
        const unsigned h  = ux & 0xFFFF0000u;
        const float l     = v[i] - __uint_as_float(h);
        bt_hi[ns + i][kr] = (short)(h >> 16);
        bt_lo[ns + i][kr] = (short)(__float_as_uint(l) >> 16);
      }
    }
    __syncthreads();

    const float* ap = inp + (size_t)(r0 + lm) * F_ + k0 + quad * 8;
    float4 aa = *(const float4*)ap;
    float4 ab = *(const float4*)(ap + 4);
    float av[8] = {aa.x, aa.y, aa.z, aa.w, ab.x, ab.y, ab.z, ab.w};
    short8 ahi, alo;
#pragma unroll
    for (int i = 0; i < 8; ++i) {
      const unsigned ux = __float_as_uint(av[i]);
      const unsigned h  = ux & 0xFFFF0000u;
      const float l     = av[i] - __uint_as_float(h);
      ahi[i] = (short)(h >> 16);
      alo[i] = (short)(__float_as_uint(l) >> 16);
    }

#pragma unroll
    for (int nt = 0; nt < 4; ++nt) {
      short8 bhi = *(const short8*)&bt_hi[nt * 16 + lm][quad * 8];
      short8 blo = *(const short8*)&bt_lo[nt * 16 + lm][quad * 8];
      c[nt] = __builtin_amdgcn_mfma_f32_16x16x32_bf16(ahi, bhi, c[nt], 0, 0, 0);
      c[nt] = __builtin_amdgcn_mfma_f32_16x16x32_bf16(ahi, blo, c[nt], 0, 0, 0);
      c[nt] = __builtin_amdgcn_mfma_f32_16x16x32_bf16(alo, bhi, c[nt], 0, 0, 0);
    }
    __syncthreads();
  }

#pragma unroll
  for (int nt = 0; nt < 4; ++nt) {
    const int u = n0 + nt * 16 + lm;
    const float bv = bias[u];
#pragma unroll
    for (int r = 0; r < 4; ++r) {
      const int row = r0 + quad * 4 + r;    // row = b*256 + t
      const int b   = row >> 8;
      out[(size_t)(row + b) * U_ + u] = c[nt][r] + bv;
    }
  }
}

// ---------------------------------------------------------------------------
// Kernel B: persistent recurrence. Grid = 128 WGs x 256 thr.
// Group g = blockIdx>>4 owns batch rows g*16..+16; cb = blockIdx&15 -> units
// cb*64..+64; wave nh owns 16 units, FULL K=1024 (no cross-wave reduction).
// W hi/lo fragments live in ~256 VGPRs per wave (preloaded once).
// Per step: coop-load s_{t-1} (frag-layout, 64 KB) global->LDS via relaxed
// agent-scope 8B atomic loads (sc0 sc1: coherent reads from LLC, no inv),
// ds_read_b128 frags, 96 MFMA, epilogue tanh + coherent 2B atomic stores of
// split(s_t), vmcnt(0) drain, then a 16-WG monotone-counter barrier with
// relaxed atomics only (NO threadfence -> no buffer_wbl2/inv).
// ---------------------------------------------------------------------------
__global__ __launch_bounds__(256) void recur_kernel(
    const float* __restrict__ W, float* __restrict__ out,
    int* __restrict__ wsbar, short* __restrict__ shi, short* __restrict__ slo) {
  __shared__ short lds_h[SB_REGION];   // 32 KB
  __shared__ short lds_l[SB_REGION];   // 32 KB

  const int tid  = threadIdx.x;
  const int nh   = tid >> 6;           // wave = unit sub-tile
  const int lane = tid & 63;
  const int lm   = lane & 15, quad = lane >> 4;
  const int g    = blockIdx.x >> 4;    // 0..7
  const int cb   = blockIdx.x & 15;    // 0..15
  const int u    = cb * 64 + nh * 16 + lm;

  // ---- preload W fragments (hi/lo) into registers: k = ks*32+quad*8+j ----
  short8 wh[32], wl[32];
#pragma unroll
  for (int ks = 0; ks < 32; ++ks) {
    const float* wp = W + (size_t)(ks * 32 + quad * 8) * U_ + u;
#pragma unroll
    for (int j = 0; j < 8; ++j) {
      const float x = wp[(size_t)j * U_];
      const unsigned ux = __float_as_uint(x);
      const unsigned h  = ux & 0xFFFF0000u;
      const float l     = x - __uint_as_float(h);
      wh[ks][j] = (short)(h >> 16);
      wl[ks][j] = (short)(__float_as_uint(l) >> 16);
    }
  }

  float accE[4] = {0.f, 0.f, 0.f, 0.f};
  int* const cntp = wsbar + 256 + g * 32;
  const size_t gbase = (size_t)g * 2 * SB_REGION;

  for (int t = 0; t < T_; ++t) {
    const int pr = (t + 1) & 1;        // parity holding s_{t-1}
    const int pw = t & 1;              // parity receiving s_t

    // ---- cooperative load s_{t-1}: global (coherent) -> LDS, linear copy ----
    {
      const unsigned long long* gh =
          (const unsigned long long*)(shi + gbase + (size_t)pr * SB_REGION);
      const unsigned long long* gl =
          (const unsigned long long*)(slo + gbase + (size_t)pr * SB_REGION);
      unsigned long long* lh = (unsigned long long*)lds_h;
      unsigned long long* ll = (unsigned long long*)lds_l;
#pragma unroll
      for (int i = 0; i < 16; ++i) {
        const int c4 = i * 256 + tid;    // 4096 8-byte chunks per array
        unsigned long long vh = __hip_atomic_load(gh + c4, __ATOMIC_RELAXED,
                                                  __HIP_MEMORY_SCOPE_AGENT);
        unsigned long long vl = __hip_atomic_load(gl + c4, __ATOMIC_RELAXED,
                                                  __HIP_MEMORY_SCOPE_AGENT);
        lh[c4] = vh;
        ll[c4] = vl;
      }
    }
    __syncthreads();

    // ---- 96 MFMA over full K=1024 ----
    f32x4 c = {0, 0, 0, 0};
#pragma unroll
    for (int ks = 0; ks < 32; ++ks) {
      const int off = ((ks * 4 + quad) * 16 + lm) * 8;
      short8 ah = *(const short8*)&lds_h[off];
      short8 al = *(const short8*)&lds_l[off];
      c = __builtin_amdgcn_mfma_f32_16x16x32_bf16(ah, wh[ks], c, 0, 0, 0);
      c = __builtin_amdgcn_mfma_f32_16x16x32_bf16(ah, wl[ks], c, 0, 0, 0);
      c = __builtin_amdgcn_mfma_f32_16x16x32_bf16(al, wh[ks], c, 0, 0, 0);
    }

    // ---- epilogue: s = tanh(h + y); coherent store of split(s) ----
    short* const dsth = shi + gbase + (size_t)pw * SB_REGION;
    short* const dstl = slo + gbase + (size_t)pw * SB_REGION;
#pragma unroll
    for (int r = 0; r < 4; ++r) {
      const int row15 = quad * 4 + r;
      const int growv = g * 16 + row15;
      const size_t idx = ((size_t)growv * 257 + t) * U_ + u;
      const float s = tanhf(c[r] + out[idx]);
      out[idx] = s;
      accE[r] += __expf(s);
      const unsigned ux = __float_as_uint(s);
      const unsigned h  = ux & 0xFFFF0000u;
      const float l     = s - __uint_as_float(h);
      const size_t sidx = ((size_t)(u >> 3) * 16 + row15) * 8 + (u & 7);
      __hip_atomic_store(dsth + sidx, (short)(h >> 16), __ATOMIC_RELAXED,
                         __HIP_MEMORY_SCOPE_AGENT);
      __hip_atomic_store(dstl + sidx, (short)(__float_as_uint(l) >> 16),
                         __ATOMIC_RELAXED, __HIP_MEMORY_SCOPE_AGENT);
    }
    // drain this wave's write-through stores (release without wbl2)
    asm volatile("s_waitcnt vmcnt(0)" ::: "memory");
    __syncthreads();   // all 4 waves drained before tid 0 signals

    // ---- per-group barrier (16 WGs), relaxed atomics only ----
    if (tid == 0) {
      __hip_atomic_fetch_add(cntp, 1, __ATOMIC_RELAXED, __HIP_MEMORY_SCOPE_AGENT);
      const int target = 16 * (t + 1);
      while (__hip_atomic_load(cntp, __ATOMIC_RELAXED, __HIP_MEMORY_SCOPE_AGENT)
             < target) {
        __builtin_amdgcn_s_sleep(1);
      }
    }
    __syncthreads();
  }

  // terminal: out[b, 256, u] = log(tanh(mean_t exp(s_t)))   (beta = 1)
#pragma unroll
  for (int r = 0; r < 4; ++r) {
    const int growv = g * 16 + quad * 4 + r;
    const size_t idx = ((size_t)growv * 257 + T_) * U_ + u;
    out[idx] = logf(tanhf(accE[r] * (1.0f / 256.0f)));
  }
}

extern "C" void kernel_launch(void* const* d_in, const int* in_sizes, int n_in,
                              void* d_out, int out_size, void* d_ws, size_t ws_size,
                              hipStream_t stream) {
  (void)in_sizes; (void)n_in; (void)out_size; (void)ws_size;
  const float* inp  = (const float*)d_in[0];
  const float* R    = (const float*)d_in[1];
  const float* W    = (const float*)d_in[2];
  const float* bias = (const float*)d_in[3];
  const float* x0   = (const float*)d_in[4];
  float* out = (float*)d_out;
  int*   wsbar = (int*)d_ws;
  short* shi = (short*)((char*)d_ws + 2048);
  short* slo = shi + 8 * 2 * SB_REGION;

  init_kernel<<<dim3(512), dim3(256), 0, stream>>>(x0, shi, slo, wsbar);
  hproj_kernel<<<dim3(8192), dim3(256), 0, stream>>>(inp, R, bias, out);
  recur_kernel<<<dim3(128), dim3(256), 0, stream>>>(W, out, wsbar, shi, slo);
}

// Round 4
// 2703.265 us; speedup vs baseline: 2.5316x; 1.0239x over previous
//
#include <hip/hip_runtime.h>
#include <hip/hip_bf16.h>

// Problem dims
#define B_ 128
#define T_ 256
#define F_ 512
#define U_ 1024

typedef __attribute__((ext_vector_type(8))) short short8;   // 8 bf16 MFMA A/B frag (4 VGPRs)
typedef __attribute__((ext_vector_type(4))) float f32x4;    // MFMA C/D frag
typedef unsigned long long u64;

// Workspace layout:
//   [0, 2048)        : barrier counters (cnt[g] at int offset 256 + g*32)
//   [2048, +512KB)   : s_hi[8 group][2 parity][16384]  bf16 frag-layout
//   [.. , +512KB)    : s_lo[8 group][2 parity][16384]
// Frag layout within a 16384-short region: elem (row 0..15, k 0..1023) at
//   ((k>>3)*16 + row)*8 + (k&7)  — linear-copyable to LDS; ds_read_b128
// yields MFMA A-frags directly.

#define SB_REGION 16384   // shorts per (group,parity) region

// ---------------------------------------------------------------------------
// Kernel 0: zero barrier counters; prefill parity-1 state with split(x0).
// ---------------------------------------------------------------------------
__global__ __launch_bounds__(256) void init_kernel(
    const float* __restrict__ x0, short* __restrict__ shi,
    short* __restrict__ slo, int* __restrict__ wsbar) {
  const int tid = threadIdx.x;
  if (blockIdx.x == 0) { wsbar[tid] = 0; wsbar[tid + 256] = 0; }
  const int idx = blockIdx.x * 256 + tid;   // 0..131071 = 8g * 16row * 1024k
  const int k   = idx & 1023;
  const int row = (idx >> 10) & 15;
  const int g   = idx >> 14;
  const float x = x0[k];
  const unsigned ux = __float_as_uint(x);
  const unsigned h  = ux & 0xFFFF0000u;
  const float l     = x - __uint_as_float(h);
  const size_t sidx = (size_t)(g * 2 + 1) * SB_REGION + ((size_t)(k >> 3) * 16 + row) * 8 + (k & 7);
  shi[sidx] = (short)(h >> 16);
  slo[sidx] = (short)(__float_as_uint(l) >> 16);
}

// ---------------------------------------------------------------------------
// Kernel A: h[b,t,u] = inputs[b,t,:] @ R[:,u] + bias[u] -> out[(b*257+t)*1024+u]
// (unchanged — passed correctness in rounds 2/3).
// ---------------------------------------------------------------------------
__global__ __launch_bounds__(256) void hproj_kernel(
    const float* __restrict__ inp, const float* __restrict__ R,
    const float* __restrict__ bias, float* __restrict__ out) {
  __shared__ short bt_hi[64][40];
  __shared__ short bt_lo[64][40];

  const int tid  = threadIdx.x;
  const int mblk = blockIdx.x >> 4;
  const int nblk = blockIdx.x & 15;
  const int n0   = nblk * 64;
  const int wave = tid >> 6, lane = tid & 63;
  const int lm   = lane & 15, quad = lane >> 4;
  const int r0   = mblk * 64 + wave * 16;

  f32x4 c[4] = {{0,0,0,0},{0,0,0,0},{0,0,0,0},{0,0,0,0}};

  for (int kc = 0; kc < 16; ++kc) {
    const int k0 = kc * 32;
    {
      const int kr = tid >> 3;
      const int ns = (tid & 7) * 8;
      const float* p = R + (size_t)(k0 + kr) * U_ + n0 + ns;
      float4 va = *(const float4*)p;
      float4 vb = *(const float4*)(p + 4);
      float v[8] = {va.x, va.y, va.z, va.w, vb.x, vb.y, vb.z, vb.w};
#pragma unroll
      for (int i = 0; i < 8; ++i) {
        const unsigned ux = __float_as_uint(v[i]);
        const unsigned h  = ux & 0xFFFF0000u;
        const float l     = v[i] - __uint_as_float(h);
        bt_hi[ns + i][kr] = (short)(h >> 16);
        bt_lo[ns + i][kr] = (short)(__float_as_uint(l) >> 16);
      }
    }
    __syncthreads();

    const float* ap = inp + (size_t)(r0 + lm) * F_ + k0 + quad * 8;
    float4 aa = *(const float4*)ap;
    float4 ab = *(const float4*)(ap + 4);
    float av[8] = {aa.x, aa.y, aa.z, aa.w, ab.x, ab.y, ab.z, ab.w};
    short8 ahi, alo;
#pragma unroll
    for (int i = 0; i < 8; ++i) {
      const unsigned ux = __float_as_uint(av[i]);
      const unsigned h  = ux & 0xFFFF0000u;
      const float l     = av[i] - __uint_as_float(h);
      ahi[i] = (short)(h >> 16);
      alo[i] = (short)(__float_as_uint(l) >> 16);
    }

#pragma unroll
    for (int nt = 0; nt < 4; ++nt) {
      short8 bhi = *(const short8*)&bt_hi[nt * 16 + lm][quad * 8];
      short8 blo = *(const short8*)&bt_lo[nt * 16 + lm][quad * 8];
      c[nt] = __builtin_amdgcn_mfma_f32_16x16x32_bf16(ahi, bhi, c[nt], 0, 0, 0);
      c[nt] = __builtin_amdgcn_mfma_f32_16x16x32_bf16(ahi, blo, c[nt], 0, 0, 0);
      c[nt] = __builtin_amdgcn_mfma_f32_16x16x32_bf16(alo, bhi, c[nt], 0, 0, 0);
    }
    __syncthreads();
  }

#pragma unroll
  for (int nt = 0; nt < 4; ++nt) {
    const int u = n0 + nt * 16 + lm;
    const float bv = bias[u];
#pragma unroll
    for (int r = 0; r < 4; ++r) {
      const int row = r0 + quad * 4 + r;    // row = b*256 + t
      const int b   = row >> 8;
      out[(size_t)(row + b) * U_ + u] = c[nt][r] + bv;
    }
  }
}

// ---------------------------------------------------------------------------
// Kernel B: persistent recurrence. Grid = 64 WGs x 512 thr (8 waves).
// Group g = blockIdx>>3 owns batch rows g*16..+16; cb = blockIdx&7 -> units
// cb*128..+128; wave nh owns 16 units, full K=1024 (no cross-wave reduce).
// W hi/lo fragments in ~256 regs/wave (AGPR-backed), preloaded once.
// Per step:
//   - prefetch h (plain loads, own out slots)
//   - BATCHED coherent load of s_{t-1}: 16x 8B agent-scope atomic loads into
//     regs back-to-back (ONE LLC round trip), then dump to LDS
//   - 96 MFMA per wave
//   - epilogue: s = tanh(h+y); plain store to out; stage s in LDS; coop
//     split+pack -> ONE 8B atomic store per thread per array
//   - vmcnt drain; 8-WG monotone-counter barrier (last arriver skips poll)
// ---------------------------------------------------------------------------
__global__ __launch_bounds__(512) void recur_kernel(
    const float* __restrict__ W, float* __restrict__ out,
    int* __restrict__ wsbar, short* __restrict__ shi, short* __restrict__ slo) {
  __shared__ short lds_h[SB_REGION];      // 32 KB
  __shared__ short lds_l[SB_REGION];      // 32 KB
  __shared__ float sstage[16 * 128];      // 8 KB  [row][u128]

  const int tid  = threadIdx.x;
  const int nh   = tid >> 6;              // wave 0..7
  const int lane = tid & 63;
  const int lm   = lane & 15, quad = lane >> 4;
  const int g    = blockIdx.x >> 3;       // 0..7
  const int cb   = blockIdx.x & 7;        // 0..7
  const int u    = cb * 128 + nh * 16 + lm;

  // ---- preload W fragments (hi/lo): k = ks*32 + quad*8 + j ----
  short8 wh[32], wl[32];
#pragma unroll
  for (int ks = 0; ks < 32; ++ks) {
    const float* wp = W + (size_t)(ks * 32 + quad * 8) * U_ + u;
#pragma unroll
    for (int j = 0; j < 8; ++j) {
      const float x = wp[(size_t)j * U_];
      const unsigned ux = __float_as_uint(x);
      const unsigned h  = ux & 0xFFFF0000u;
      const float l     = x - __uint_as_float(h);
      wh[ks][j] = (short)(h >> 16);
      wl[ks][j] = (short)(__float_as_uint(l) >> 16);
    }
  }

  float accE[4] = {0.f, 0.f, 0.f, 0.f};
  int* const cntp = wsbar + 256 + g * 32;
  const size_t gbase = (size_t)g * 2 * SB_REGION;

  // coop-store mapping: thread handles 4 consecutive sstage elems
  const int cs_row = (tid * 4) >> 7;          // 0..15
  const int cs_u   = (tid * 4) & 127;         // multiple of 4
  const int cs_ug  = cb * 128 + cs_u;         // global unit, %4 == 0
  const size_t cs_dst = ((size_t)(cs_ug >> 3) * 16 + cs_row) * 8 + (cs_ug & 7); // 8B-aligned

  for (int t = 0; t < T_; ++t) {
    const int pr = (t + 1) & 1;        // parity holding s_{t-1}
    const int pw = t & 1;              // parity receiving s_t

    // ---- prefetch h (plain loads; overlap with state round trip) ----
    float hv[4];
#pragma unroll
    for (int r = 0; r < 4; ++r) {
      const int row = g * 16 + quad * 4 + r;
      hv[r] = out[((size_t)row * 257 + t) * U_ + u];
    }

    // ---- batched coherent load of s_{t-1} into regs, then LDS ----
    {
      const u64* gh = (const u64*)(shi + gbase + (size_t)pr * SB_REGION);
      const u64* gl = (const u64*)(slo + gbase + (size_t)pr * SB_REGION);
      u64 rh[8], rl[8];
#pragma unroll
      for (int i = 0; i < 8; ++i)
        rh[i] = __hip_atomic_load(gh + i * 512 + tid, __ATOMIC_RELAXED,
                                  __HIP_MEMORY_SCOPE_AGENT);
#pragma unroll
      for (int i = 0; i < 8; ++i)
        rl[i] = __hip_atomic_load(gl + i * 512 + tid, __ATOMIC_RELAXED,
                                  __HIP_MEMORY_SCOPE_AGENT);
      u64* lh = (u64*)lds_h;
      u64* ll = (u64*)lds_l;
#pragma unroll
      for (int i = 0; i < 8; ++i) lh[i * 512 + tid] = rh[i];
#pragma unroll
      for (int i = 0; i < 8; ++i) ll[i * 512 + tid] = rl[i];
    }
    __syncthreads();

    // ---- 96 MFMA over full K=1024 ----
    f32x4 c = {0, 0, 0, 0};
#pragma unroll
    for (int ks = 0; ks < 32; ++ks) {
      const int off = ((ks * 4 + quad) * 16 + lm) * 8;
      short8 ah = *(const short8*)&lds_h[off];
      short8 al = *(const short8*)&lds_l[off];
      c = __builtin_amdgcn_mfma_f32_16x16x32_bf16(ah, wh[ks], c, 0, 0, 0);
      c = __builtin_amdgcn_mfma_f32_16x16x32_bf16(ah, wl[ks], c, 0, 0, 0);
      c = __builtin_amdgcn_mfma_f32_16x16x32_bf16(al, wh[ks], c, 0, 0, 0);
    }
    __syncthreads();   // lds_h/lds_l reads done before sstage phase races next load

    // ---- epilogue: s = tanh(h + y); plain out store; stage in LDS ----
#pragma unroll
    for (int r = 0; r < 4; ++r) {
      const int row15 = quad * 4 + r;
      const int row   = g * 16 + row15;
      const float s   = tanhf(c[r] + hv[r]);
      out[((size_t)row * 257 + t) * U_ + u] = s;
      accE[r] += __expf(s);
      sstage[row15 * 128 + (nh * 16 + lm)] = s;
    }
    __syncthreads();

    // ---- coop split/pack: one 8B atomic store per thread per array ----
    {
      float4 sv = *(const float4*)&sstage[tid * 4];
      float v[4] = {sv.x, sv.y, sv.z, sv.w};
      u64 ph = 0, pl = 0;
#pragma unroll
      for (int j = 0; j < 4; ++j) {
        const unsigned ux = __float_as_uint(v[j]);
        const unsigned h  = ux & 0xFFFF0000u;
        const float l     = v[j] - __uint_as_float(h);
        ph |= (u64)(unsigned short)(h >> 16) << (16 * j);
        pl |= (u64)(unsigned short)(__float_as_uint(l) >> 16) << (16 * j);
      }
      u64* dsth = (u64*)(shi + gbase + (size_t)pw * SB_REGION + cs_dst);
      u64* dstl = (u64*)(slo + gbase + (size_t)pw * SB_REGION + cs_dst);
      __hip_atomic_store(dsth, ph, __ATOMIC_RELAXED, __HIP_MEMORY_SCOPE_AGENT);
      __hip_atomic_store(dstl, pl, __ATOMIC_RELAXED, __HIP_MEMORY_SCOPE_AGENT);
    }
    asm volatile("s_waitcnt vmcnt(0)" ::: "memory");
    __syncthreads();   // all waves drained before tid 0 signals

    // ---- per-group barrier (8 WGs), relaxed monotone counter ----
    if (tid == 0) {
      const int prev = __hip_atomic_fetch_add(cntp, 1, __ATOMIC_RELAXED,
                                              __HIP_MEMORY_SCOPE_AGENT);
      const int target = 8 * (t + 1);
      if (prev != target - 1) {
        while (__hip_atomic_load(cntp, __ATOMIC_RELAXED,
                                 __HIP_MEMORY_SCOPE_AGENT) < target) {
          __builtin_amdgcn_s_sleep(1);
        }
      }
    }
    __syncthreads();
  }

  // terminal: out[b, 256, u] = log(tanh(mean_t exp(s_t)))   (beta = 1)
#pragma unroll
  for (int r = 0; r < 4; ++r) {
    const int row = g * 16 + quad * 4 + r;
    out[((size_t)row * 257 + T_) * U_ + u] = logf(tanhf(accE[r] * (1.0f / 256.0f)));
  }
}

extern "C" void kernel_launch(void* const* d_in, const int* in_sizes, int n_in,
                              void* d_out, int out_size, void* d_ws, size_t ws_size,
                              hipStream_t stream) {
  (void)in_sizes; (void)n_in; (void)out_size; (void)ws_size;
  const float* inp  = (const float*)d_in[0];
  const float* R    = (const float*)d_in[1];
  const float* W    = (const float*)d_in[2];
  const float* bias = (const float*)d_in[3];
  const float* x0   = (const float*)d_in[4];
  float* out = (float*)d_out;
  int*   wsbar = (int*)d_ws;
  short* shi = (short*)((char*)d_ws + 2048);
  short* slo = shi + 8 * 2 * SB_REGION;

  init_kernel<<<dim3(512), dim3(256), 0, stream>>>(x0, shi, slo, wsbar);
  hproj_kernel<<<dim3(8192), dim3(256), 0, stream>>>(inp, R, bias, out);
  recur_kernel<<<dim3(64), dim3(512), 0, stream>>>(W, out, wsbar, shi, slo);
}

// Round 5
// 1399.010 us; speedup vs baseline: 4.8918x; 1.9323x over previous
//
#include <hip/hip_runtime.h>
#include <hip/hip_bf16.h>

// Problem dims
#define B_ 128
#define T_ 256
#define F_ 512
#define U_ 1024

typedef __attribute__((ext_vector_type(8))) short short8;   // 8 bf16 MFMA A/B frag (4 VGPRs)
typedef __attribute__((ext_vector_type(4))) float f32x4;    // MFMA C/D frag
typedef unsigned long long u64;

// Workspace layout (~5.1 MB):
//   [0, 2048)          : barrier counters (cnt[g] at int offset 256 + g*32)
//   [2048, +512KB)     : s_hi[8 group][2 parity][16384] bf16 frag-layout
//   [+512KB)           : s_lo  (same shape)
//   [+2MB)             : wsWh[1024x1024] bf16, B-frag layout (see winit)
//   [+2MB)             : wsWl
// State frag layout within a 16384-short region: elem (row 0..15, k 0..1023)
// at ((k>>3)*16 + row)*8 + (k&7) — linear-copyable to LDS; ds_read_b128
// yields MFMA A-frags directly.

#define SB_REGION 16384   // shorts per (group,parity) state region

// ---------------------------------------------------------------------------
// Kernel 0a: zero barrier counters; prefill parity-1 state with split(x0).
// ---------------------------------------------------------------------------
__global__ __launch_bounds__(256) void init_kernel(
    const float* __restrict__ x0, short* __restrict__ shi,
    short* __restrict__ slo, int* __restrict__ wsbar) {
  const int tid = threadIdx.x;
  if (blockIdx.x == 0) { wsbar[tid] = 0; wsbar[tid + 256] = 0; }
  const int idx = blockIdx.x * 256 + tid;   // 0..131071 = 8g * 16row * 1024k
  const int k   = idx & 1023;
  const int row = (idx >> 10) & 15;
  const int g   = idx >> 14;
  const float x = x0[k];
  const unsigned ux = __float_as_uint(x);
  const unsigned h  = ux & 0xFFFF0000u;
  const float l     = x - __uint_as_float(h);
  const size_t sidx = (size_t)(g * 2 + 1) * SB_REGION + ((size_t)(k >> 3) * 16 + row) * 8 + (k & 7);
  shi[sidx] = (short)(h >> 16);
  slo[sidx] = (short)(__float_as_uint(l) >> 16);
}

// ---------------------------------------------------------------------------
// Kernel 0b: pre-split W into bf16 hi/lo in B-frag layout so recur's one-time
// register preload is pure coalesced dwordx4 loads (no VALU split anywhere
// near the hot loop). For wave (cb,nt,kh), frag ks, lane ln, elem j:
//   k = kh*512 + ks*32 + (ln>>4)*8 + j,  u = cb*64 + nt*16 + (ln&15)
//   wsW[((((cb*4+nt)*2+kh)*16 + ks)*64 + ln)*8 + j]
// ---------------------------------------------------------------------------
__global__ __launch_bounds__(256) void winit_kernel(
    const float* __restrict__ W, short* __restrict__ wsWh,
    short* __restrict__ wsWl) {
  const int idx = blockIdx.x * 256 + threadIdx.x;   // 0..1048575
  const int u = idx & 1023;
  const int k = idx >> 10;
  const float x = W[(size_t)k * U_ + u];
  const unsigned ux = __float_as_uint(x);
  const unsigned h  = ux & 0xFFFF0000u;
  const float l     = x - __uint_as_float(h);
  const int cb = u >> 6, nt = (u >> 4) & 3;
  const int kh = k >> 9, ks = (k >> 5) & 15;
  const int ln = (((k >> 3) & 3) << 4) | (u & 15);
  const size_t w = ((size_t)((((cb * 4 + nt) * 2 + kh) * 16 + ks)) * 64 + ln) * 8 + (k & 7);
  wsWh[w] = (short)(h >> 16);
  wsWl[w] = (short)(__float_as_uint(l) >> 16);
}

// ---------------------------------------------------------------------------
// Kernel A: h[b,t,u] = inputs[b,t,:] @ R[:,u] + bias[u] -> out[(b*257+t)*1024+u]
// (unchanged — passed correctness rounds 2-4).
// ---------------------------------------------------------------------------
__global__ __launch_bounds__(256) void hproj_kernel(
    const float* __restrict__ inp, const float* __restrict__ R,
    const float* __restrict__ bias, float* __restrict__ out) {
  __shared__ short bt_hi[64][40];
  __shared__ short bt_lo[64][40];

  const int tid  = threadIdx.x;
  const int mblk = blockIdx.x >> 4;
  const int nblk = blockIdx.x & 15;
  const int n0   = nblk * 64;
  const int wave = tid >> 6, lane = tid & 63;
  const int lm   = lane & 15, quad = lane >> 4;
  const int r0   = mblk * 64 + wave * 16;

  f32x4 c[4] = {{0,0,0,0},{0,0,0,0},{0,0,0,0},{0,0,0,0}};

  for (int kc = 0; kc < 16; ++kc) {
    const int k0 = kc * 32;
    {
      const int kr = tid >> 3;
      const int ns = (tid & 7) * 8;
      const float* p = R + (size_t)(k0 + kr) * U_ + n0 + ns;
      float4 va = *(const float4*)p;
      float4 vb = *(const float4*)(p + 4);
      float v[8] = {va.x, va.y, va.z, va.w, vb.x, vb.y, vb.z, vb.w};
#pragma unroll
      for (int i = 0; i < 8; ++i) {
        const unsigned ux = __float_as_uint(v[i]);
        const unsigned h  = ux & 0xFFFF0000u;
        const float l     = v[i] - __uint_as_float(h);
        bt_hi[ns + i][kr] = (short)(h >> 16);
        bt_lo[ns + i][kr] = (short)(__float_as_uint(l) >> 16);
      }
    }
    __syncthreads();

    const float* ap = inp + (size_t)(r0 + lm) * F_ + k0 + quad * 8;
    float4 aa = *(const float4*)ap;
    float4 ab = *(const float4*)(ap + 4);
    float av[8] = {aa.x, aa.y, aa.z, aa.w, ab.x, ab.y, ab.z, ab.w};
    short8 ahi, alo;
#pragma unroll
    for (int i = 0; i < 8; ++i) {
      const unsigned ux = __float_as_uint(av[i]);
      const unsigned h  = ux & 0xFFFF0000u;
      const float l     = av[i] - __uint_as_float(h);
      ahi[i] = (short)(h >> 16);
      alo[i] = (short)(__float_as_uint(l) >> 16);
    }

#pragma unroll
    for (int nt = 0; nt < 4; ++nt) {
      short8 bhi = *(const short8*)&bt_hi[nt * 16 + lm][quad * 8];
      short8 blo = *(const short8*)&bt_lo[nt * 16 + lm][quad * 8];
      c[nt] = __builtin_amdgcn_mfma_f32_16x16x32_bf16(ahi, bhi, c[nt], 0, 0, 0);
      c[nt] = __builtin_amdgcn_mfma_f32_16x16x32_bf16(ahi, blo, c[nt], 0, 0, 0);
      c[nt] = __builtin_amdgcn_mfma_f32_16x16x32_bf16(alo, bhi, c[nt], 0, 0, 0);
    }
    __syncthreads();
  }

#pragma unroll
  for (int nt = 0; nt < 4; ++nt) {
    const int u = n0 + nt * 16 + lm;
    const float bv = bias[u];
#pragma unroll
    for (int r = 0; r < 4; ++r) {
      const int row = r0 + quad * 4 + r;    // row = b*256 + t
      const int b   = row >> 8;
      out[(size_t)(row + b) * U_ + u] = c[nt][r] + bv;
    }
  }
}

// ---------------------------------------------------------------------------
// Kernel B: persistent recurrence. Grid = 128 WGs x 512 thr (8 waves).
// __launch_bounds__(512,2) -> 2 waves/EU -> 256-VGPR budget: W frags (128
// VGPRs, K-split) provably fit -> no spill, no in-loop W traffic.
// Group g = blockIdx&7 owns batch rows g*16..+16 (16 WGs/group, XCD
// co-located); cb = blockIdx>>3 -> units cb*64..+64.
// Wave wv: nt = wv&3 (16-unit tile), kh = wv>>2 (512-wide K half).
// Per step: prefetch h; batched agent-atomic load of s_{t-1} -> LDS;
// 48 MFMA/wave; kh1 -> red, kh0 -> epilogue (tanh, out store, sstage);
// kh1 waves pack sstage -> ONE 8B coherent store per thread per array;
// vmcnt drain; 16-WG monotone-counter barrier.
// ---------------------------------------------------------------------------
__global__ __launch_bounds__(512, 2) void recur_kernel(
    const short* __restrict__ wsWh, const short* __restrict__ wsWl,
    float* __restrict__ out, int* __restrict__ wsbar,
    short* __restrict__ shi, short* __restrict__ slo) {
  __shared__ short lds_h[SB_REGION];      // 32 KB
  __shared__ short lds_l[SB_REGION];      // 32 KB
  __shared__ float red[4 * 64 * 4];       // 4 KB  [nt][lane][4]
  __shared__ float sstage[16 * 64];       // 4 KB  [row][u64]

  const int tid  = threadIdx.x;
  const int wv   = tid >> 6, lane = tid & 63;
  const int lm   = lane & 15, quad = lane >> 4;
  const int nt   = wv & 3, kh = wv >> 2;
  const int g    = blockIdx.x & 7;        // group (XCD co-located)
  const int cb   = blockIdx.x >> 3;       // 0..15
  const int u    = cb * 64 + nt * 16 + lm;

  // ---- one-time W fragment preload: 32 coalesced dwordx4 loads ----
  short8 wh[16], wl[16];
  {
    const size_t wbase = ((size_t)(((cb * 4 + nt) * 2 + kh) * 16) * 64 + lane) * 8;
#pragma unroll
    for (int ks = 0; ks < 16; ++ks) {
      wh[ks] = *(const short8*)(wsWh + wbase + (size_t)ks * 512);
      wl[ks] = *(const short8*)(wsWl + wbase + (size_t)ks * 512);
    }
  }

  float accE[4] = {0.f, 0.f, 0.f, 0.f};
  int* const cntp = wsbar + 256 + g * 32;
  const size_t gbase = (size_t)g * 2 * SB_REGION;

  // pack mapping (kh==1 waves, local id pt = tid-256 in 0..255): 4 elems each
  const int pt     = tid & 255;
  const int cs_row = (pt * 4) >> 6;           // 0..15
  const int cs_ug  = cb * 64 + ((pt * 4) & 63);
  const size_t cs_dst = ((size_t)(cs_ug >> 3) * 16 + cs_row) * 8 + (cs_ug & 7); // 8B-aligned

  for (int t = 0; t < T_; ++t) {
    const int pr = (t + 1) & 1;        // parity holding s_{t-1}
    const int pw = t & 1;              // parity receiving s_t

    // ---- prefetch h (plain loads; overlap with state round trip) ----
    float hv[4] = {0.f, 0.f, 0.f, 0.f};
    if (kh == 0) {
#pragma unroll
      for (int r = 0; r < 4; ++r) {
        const int row = g * 16 + quad * 4 + r;
        hv[r] = out[((size_t)row * 257 + t) * U_ + u];
      }
    }

    // ---- batched coherent load of s_{t-1} into regs, then LDS ----
    {
      const u64* gh = (const u64*)(shi + gbase + (size_t)pr * SB_REGION);
      const u64* gl = (const u64*)(slo + gbase + (size_t)pr * SB_REGION);
      u64 rh[8], rl[8];
#pragma unroll
      for (int i = 0; i < 8; ++i)
        rh[i] = __hip_atomic_load(gh + i * 512 + tid, __ATOMIC_RELAXED,
                                  __HIP_MEMORY_SCOPE_AGENT);
#pragma unroll
      for (int i = 0; i < 8; ++i)
        rl[i] = __hip_atomic_load(gl + i * 512 + tid, __ATOMIC_RELAXED,
                                  __HIP_MEMORY_SCOPE_AGENT);
      u64* lh = (u64*)lds_h;
      u64* ll = (u64*)lds_l;
#pragma unroll
      for (int i = 0; i < 8; ++i) lh[i * 512 + tid] = rh[i];
#pragma unroll
      for (int i = 0; i < 8; ++i) ll[i * 512 + tid] = rl[i];
    }
    __syncthreads();   // S1: state staged

    // ---- 48 MFMA over this wave's K half ----
    f32x4 c = {0, 0, 0, 0};
#pragma unroll
    for (int ks = 0; ks < 16; ++ks) {
      const int off = (((kh * 16 + ks) * 4 + quad) * 16 + lm) * 8;
      short8 ah = *(const short8*)&lds_h[off];
      short8 al = *(const short8*)&lds_l[off];
      c = __builtin_amdgcn_mfma_f32_16x16x32_bf16(ah, wh[ks], c, 0, 0, 0);
      c = __builtin_amdgcn_mfma_f32_16x16x32_bf16(ah, wl[ks], c, 0, 0, 0);
      c = __builtin_amdgcn_mfma_f32_16x16x32_bf16(al, wh[ks], c, 0, 0, 0);
    }
    if (kh == 1) *(f32x4*)&red[(nt * 64 + lane) * 4] = c;
    __syncthreads();   // S2: red visible; all LDS state reads complete

    // ---- epilogue on kh0 waves: s = tanh(h + y); out store; stage s ----
    if (kh == 0) {
      f32x4 p = *(const f32x4*)&red[(nt * 64 + lane) * 4];
      c += p;
#pragma unroll
      for (int r = 0; r < 4; ++r) {
        const int row15 = quad * 4 + r;
        const int row   = g * 16 + row15;
        const float s   = tanhf(c[r] + hv[r]);
        out[((size_t)row * 257 + t) * U_ + u] = s;
        accE[r] += __expf(s);
        sstage[row15 * 64 + (nt * 16 + lm)] = s;
      }
    }
    __syncthreads();   // S3: sstage visible

    // ---- pack on kh1 waves: split + ONE 8B coherent store per array ----
    if (kh == 1) {
      float4 sv = *(const float4*)&sstage[pt * 4];
      float v[4] = {sv.x, sv.y, sv.z, sv.w};
      u64 ph = 0, pl = 0;
#pragma unroll
      for (int j = 0; j < 4; ++j) {
        const unsigned ux = __float_as_uint(v[j]);
        const unsigned h  = ux & 0xFFFF0000u;
        const float l     = v[j] - __uint_as_float(h);
        ph |= (u64)(unsigned short)(h >> 16) << (16 * j);
        pl |= (u64)(unsigned short)(__float_as_uint(l) >> 16) << (16 * j);
      }
      u64* dsth = (u64*)(shi + gbase + (size_t)pw * SB_REGION + cs_dst);
      u64* dstl = (u64*)(slo + gbase + (size_t)pw * SB_REGION + cs_dst);
      __hip_atomic_store(dsth, ph, __ATOMIC_RELAXED, __HIP_MEMORY_SCOPE_AGENT);
      __hip_atomic_store(dstl, pl, __ATOMIC_RELAXED, __HIP_MEMORY_SCOPE_AGENT);
    }
    asm volatile("s_waitcnt vmcnt(0)" ::: "memory");
    __syncthreads();   // S4: all WG stores drained

    // ---- per-group barrier (16 WGs), relaxed monotone counter ----
    if (tid == 0) {
      const int prev = __hip_atomic_fetch_add(cntp, 1, __ATOMIC_RELAXED,
                                              __HIP_MEMORY_SCOPE_AGENT);
      const int target = 16 * (t + 1);
      if (prev != target - 1) {
        while (__hip_atomic_load(cntp, __ATOMIC_RELAXED,
                                 __HIP_MEMORY_SCOPE_AGENT) < target) {
          __builtin_amdgcn_s_sleep(1);
        }
      }
    }
    __syncthreads();   // S5: release
  }

  // terminal: out[b, 256, u] = log(tanh(mean_t exp(s_t)))   (beta = 1)
  if (kh == 0) {
#pragma unroll
    for (int r = 0; r < 4; ++r) {
      const int row = g * 16 + quad * 4 + r;
      out[((size_t)row * 257 + T_) * U_ + u] = logf(tanhf(accE[r] * (1.0f / 256.0f)));
    }
  }
}

extern "C" void kernel_launch(void* const* d_in, const int* in_sizes, int n_in,
                              void* d_out, int out_size, void* d_ws, size_t ws_size,
                              hipStream_t stream) {
  (void)in_sizes; (void)n_in; (void)out_size; (void)ws_size;
  const float* inp  = (const float*)d_in[0];
  const float* R    = (const float*)d_in[1];
  const float* W    = (const float*)d_in[2];
  const float* bias = (const float*)d_in[3];
  const float* x0   = (const float*)d_in[4];
  float* out = (float*)d_out;
  int*   wsbar = (int*)d_ws;
  short* shi  = (short*)((char*)d_ws + 2048);
  short* slo  = shi + 8 * 2 * SB_REGION;            // +512 KB
  short* wsWh = slo + 8 * 2 * SB_REGION;            // +512 KB
  short* wsWl = wsWh + 1024 * 1024;                 // +2 MB

  init_kernel<<<dim3(512), dim3(256), 0, stream>>>(x0, shi, slo, wsbar);
  winit_kernel<<<dim3(4096), dim3(256), 0, stream>>>(W, wsWh, wsWl);
  hproj_kernel<<<dim3(8192), dim3(256), 0, stream>>>(inp, R, bias, out);
  recur_kernel<<<dim3(128), dim3(512), 0, stream>>>(wsWh, wsWl, out, wsbar, shi, slo);
}